// Round 11
// baseline (802.923 us; speedup 1.0000x reference)
//
#include <hip/hip_runtime.h>

typedef _Float16 f16x8 __attribute__((ext_vector_type(8)));
typedef _Float16 f16x4 __attribute__((ext_vector_type(4)));
typedef float    f32x4 __attribute__((ext_vector_type(4)));

// ---------------------------------------------------------------- helpers

__device__ __forceinline__ void async16(void* lds, const void* g) {
    __builtin_amdgcn_global_load_lds(
        (const __attribute__((address_space(1))) unsigned int*)g,
        (__attribute__((address_space(3))) unsigned int*)lds, 16, 0, 0);
}

#define MEMF() asm volatile("" ::: "memory")
__device__ __forceinline__ void BAR() { MEMF(); __builtin_amdgcn_s_barrier(); MEMF(); }
#define VMWAIT(N) asm volatile("s_waitcnt vmcnt(" #N ")" ::: "memory")

// swizzled LDS fragment read: tile row-major [256 rows][64B], byte col XORed by
// ((row>>1)&3)<<4 -> conflict-free (measured 0 in SQ_LDS_BANK_CONFLICT, r4/r8)
__device__ __forceinline__ f16x8 frag_ld(const _Float16* buf, int row, int kq) {
    const char* p = (const char*)buf + row * 64 + ((kq << 4) ^ (((row >> 1) & 3) << 4));
    return *(const f16x8*)p;
}

// ------------------------------------------------- dbuf-2 256x256 GEMM, 2 blocks/CU
// A [M][K] fp16, BT [N][K] fp16, C = (A*BT^T)*alpha+beta  [M][N] fp32
// 8 waves (2Mx4N), BK=32, DOUBLE-buffered LDS (64KiB -> 2 blocks/CU).
// r8's proven 2-barrier skeleton. Rationale (r4-r10 counters): seven 1-block/CU
// schedules all pin at ~40% MfmaUtil -- intra-block pipelining cannot cover the
// per-tile sync/drain dead time. 64KiB LDS makes 2 blocks co-resident per CU
// (16 waves), so the sibling block's MFMAs cover this block's drains (m114
// mechanism, m97's "implicit wave-level overlap").
//
// Ledger: tile t in buf t&1. During t: stage t+1 into buf^1 (A before BAR_a,
// B mid-cluster). WAR: buf^1 held tile t-1; every wave's t-1 reads drained
// (lgkm before its MFMAs) before BAR(end t-1), stages issue after => safe.
// RAW: VMWAIT(0)+BAR at end of t => tile t+1 fully in LDS for all waves.

__global__ __launch_bounds__(512, 2) void gemm_f16_bn_db(
        const _Float16* __restrict__ A, const _Float16* __restrict__ BT,
        float* __restrict__ C,
        const float* __restrict__ bias, const float* __restrict__ mean,
        const float* __restrict__ var,  const float* __restrict__ bnw,
        const float* __restrict__ bnb,  const float* __restrict__ scalep,
        int M, int N, int K) {
    __shared__ __align__(16) _Float16 ldsA[2][8192];   // 2 x 256x32 fp16 = 32KB
    __shared__ __align__(16) _Float16 ldsB[2][8192];   // 32KB

    // bijective XCD swizzle (grid = 1024, divisible by 8)
    const int nwg = gridDim.x;
    const int cpx = nwg >> 3;
    int bid = blockIdx.x;
    int swz = ((nwg & 7) == 0) ? (bid & 7) * cpx + (bid >> 3) : bid;
    const int ntn = N >> 8;
    const int m0 = (swz / ntn) << 8, n0 = (swz % ntn) << 8;

    const int t = threadIdx.x;
    const int lane = t & 63, wid = t >> 6;
    const int wr = wid >> 2, wc = wid & 3;          // 2M x 4N waves
    const int rr = lane & 15, kq = lane >> 4;
    const int arow = wr * 128, brow = wc * 64;

    // staging: 1024 16B-chunks per operand tile; thread handles chunks t, t+512.
    // chunk c -> LDS bytes [c*16, c*16+16) (linear); source column pre-XORed so
    // the swizzled read returns linear data (both-sides-or-neither).
    const int c0 = t, c1 = t + 512;
    const int r0 = c0 >> 2, r1 = c1 >> 2;
    const int sc0 = (((c0 & 3) << 4) ^ (((r0 >> 1) & 3) << 4)) >> 1;
    const int sc1 = (((c1 & 3) << 4) ^ (((r1 >> 1) & 3) << 4)) >> 1;
    const _Float16* gA0 = A  + (size_t)(m0 + r0) * K + sc0;
    const _Float16* gA1 = A  + (size_t)(m0 + r1) * K + sc1;
    const _Float16* gB0 = BT + (size_t)(n0 + r0) * K + sc0;
    const _Float16* gB1 = BT + (size_t)(n0 + r1) * K + sc1;
    char* const adst0 = (char*)&ldsA[0][0] + (size_t)c0 * 16;
    char* const adst1 = (char*)&ldsA[0][0] + (size_t)c1 * 16;
    char* const bdst0 = (char*)&ldsB[0][0] + (size_t)c0 * 16;
    char* const bdst1 = (char*)&ldsB[0][0] + (size_t)c1 * 16;

    f32x4 acc[8][4] = {};

    const int NT = K >> 5;   // 128

    // prologue: stage tile 0 into buf 0
    async16(adst0, gA0);
    async16(adst1, gA1);
    async16(bdst0, gB0);
    async16(bdst1, gB1);
    VMWAIT(0);
    BAR();

#define TILE_STEP(SLOT, STAGE, KSRC, WAITSTMT)                                   \
  do {                                                                           \
    const _Float16* Ab = ldsA[SLOT];                                             \
    const _Float16* Bb = ldsB[SLOT];                                             \
    const int qs = (SLOT) ^ 1;                                                   \
    f16x8 af[8], bf[4];                                                          \
    /* all 12 frag reads front-loaded: waves stagger on their own lgkm waits */  \
    _Pragma("unroll")                                                            \
    for (int mi = 0; mi < 8; mi++) af[mi] = frag_ld(Ab, arow + mi * 16 + rr, kq);\
    _Pragma("unroll")                                                            \
    for (int ni = 0; ni < 4; ni++) bf[ni] = frag_ld(Bb, brow + ni * 16 + rr, kq);\
    if (STAGE) {                                                                 \
      async16(adst0 + qs * 16384, gA0 + (size_t)(KSRC) * 32);                    \
      async16(adst1 + qs * 16384, gA1 + (size_t)(KSRC) * 32);                    \
    }                                                                            \
    BAR();                                                                       \
    __builtin_amdgcn_s_setprio(1);                                               \
    _Pragma("unroll")                                                            \
    for (int ni = 0; ni < 2; ni++) {                                             \
      _Pragma("unroll")                                                          \
      for (int mi = 0; mi < 8; mi++)                                             \
        acc[mi][ni] = __builtin_amdgcn_mfma_f32_16x16x32_f16(                    \
            af[mi], bf[ni], acc[mi][ni], 0, 0, 0);                               \
    }                                                                            \
    if (STAGE) {                                                                 \
      async16(bdst0 + qs * 16384, gB0 + (size_t)(KSRC) * 32);                    \
      async16(bdst1 + qs * 16384, gB1 + (size_t)(KSRC) * 32);                    \
    }                                                                            \
    _Pragma("unroll")                                                            \
    for (int ni = 2; ni < 4; ni++) {                                             \
      _Pragma("unroll")                                                          \
      for (int mi = 0; mi < 8; mi++)                                             \
        acc[mi][ni] = __builtin_amdgcn_mfma_f32_16x16x32_f16(                    \
            af[mi], bf[ni], acc[mi][ni], 0, 0, 0);                               \
    }                                                                            \
    __builtin_amdgcn_s_setprio(0);                                               \
    WAITSTMT;                                                                    \
    BAR();                                                                       \
  } while (0)

    int ti = 0;
    for (; ti < NT - 1; ++ti)
        TILE_STEP(ti & 1, 1, ti + 1, VMWAIT(0));
    TILE_STEP(ti & 1, 0, 0, (void)0);
#undef TILE_STEP

    // fused BN-affine epilogue, nontemporal fp32 stores
    const float s = scalep[0];
    const int colb = n0 + wc * 64 + rr;
    const int rowb = m0 + wr * 128 + (kq << 2);
#pragma unroll
    for (int ni = 0; ni < 4; ni++) {
        const int col = colb + ni * 16;
        const float rv    = rsqrtf(var[col] + 1e-5f);
        const float alpha = rv * bnw[col] * s;
        const float beta  = (bias[col] - mean[col]) * alpha + bnb[col] * s;
#pragma unroll
        for (int mi = 0; mi < 8; mi++)
#pragma unroll
            for (int i = 0; i < 4; i++)
                __builtin_nontemporal_store(acc[mi][ni][i] * alpha + beta,
                    &C[(size_t)(rowb + mi * 16 + i) * N + col]);
    }
}

// ---------------------------------------------------------------- converts

__global__ __launch_bounds__(256) void cvt_x_kernel(const float4* __restrict__ in,
                                                    f16x4* __restrict__ outp, long n4) {
    long i = (long)blockIdx.x * blockDim.x + threadIdx.x;
    const long stride = (long)gridDim.x * blockDim.x;
    for (; i < n4; i += stride) {
        float4 v = in[i];
        f16x4 h = { (_Float16)v.x, (_Float16)v.y, (_Float16)v.z, (_Float16)v.w };
        outp[i] = h;
    }
}

// w [K][N] fp32 -> wt [N][K] fp16
__global__ __launch_bounds__(256) void transpose_w_kernel(const float* __restrict__ w,
                                                          _Float16* __restrict__ wt,
                                                          int K, int N) {
    __shared__ _Float16 tile[32][33];
    const int n0 = blockIdx.x * 32;
    const int k0 = blockIdx.y * 32;
    for (int i = threadIdx.y; i < 32; i += 8)
        tile[i][threadIdx.x] = (_Float16)w[(size_t)(k0 + i) * N + n0 + threadIdx.x];
    __syncthreads();
    for (int i = threadIdx.y; i < 32; i += 8)
        wt[(size_t)(n0 + i) * K + k0 + threadIdx.x] = tile[threadIdx.x][i];
}

// ------------------------------------------------- fallback GEMM (no ws)

__device__ __forceinline__ void mfma_step_128(const _Float16* As, const _Float16* Bs,
                                              f32x4 (&acc)[4][4], int lane, int wr, int wc) {
    const int kk = (lane >> 4) * 8;
    const int rr = lane & 15;
    f16x8 af[4], bf[4];
#pragma unroll
    for (int mi = 0; mi < 4; mi++)
        af[mi] = *(const f16x8*)(As + (size_t)(wr * 64 + mi * 16 + rr) * 32 + kk);
#pragma unroll
    for (int ni = 0; ni < 4; ni++)
        bf[ni] = *(const f16x8*)(Bs + (size_t)(wc * 64 + ni * 16 + rr) * 32 + kk);
#pragma unroll
    for (int mi = 0; mi < 4; mi++)
#pragma unroll
        for (int ni = 0; ni < 4; ni++)
            acc[mi][ni] = __builtin_amdgcn_mfma_f32_16x16x32_f16(af[mi], bf[ni], acc[mi][ni], 0, 0, 0);
}

__global__ __launch_bounds__(256) void gemm_f32src_bn(const float* __restrict__ X,
                                                      const float* __restrict__ W,
                                                      float* __restrict__ C,
                                                      const float* __restrict__ bias,
                                                      const float* __restrict__ mean,
                                                      const float* __restrict__ var,
                                                      const float* __restrict__ bnw,
                                                      const float* __restrict__ bnb,
                                                      const float* __restrict__ scalep,
                                                      int M, int N, int K) {
    __shared__ _Float16 As[128 * 32];
    __shared__ _Float16 Bs[128 * 32];

    const int nwg = gridDim.x;
    const int cpx = nwg >> 3;
    int bid = blockIdx.x;
    int swz = ((nwg & 7) == 0) ? (bid & 7) * cpx + (bid >> 3) : bid;
    const int ntn = N / 128;
    const int m0 = (swz / ntn) * 128, n0 = (swz % ntn) * 128;

    const int t = threadIdx.x;
    const int lane = t & 63, w = t >> 6;
    const int wr = w >> 1, wc = w & 1;

    f32x4 acc[4][4] = {};

    for (int k0 = 0; k0 < K; k0 += 32) {
        __syncthreads();
#pragma unroll
        for (int p = 0; p < 4; p++) {
            const int r = p * 32 + (t >> 3);
            const int c = (t & 7) * 4;
            float4 v = *(const float4*)&X[(size_t)(m0 + r) * K + k0 + c];
            f16x4 h = { (_Float16)v.x, (_Float16)v.y, (_Float16)v.z, (_Float16)v.w };
            *(f16x4*)&As[(size_t)r * 32 + c] = h;
        }
#pragma unroll
        for (int p = 0; p < 4; p++) {
            const int kk = p * 8 + (t >> 5);
            const int nn = (t & 31) * 4;
            float4 v = *(const float4*)&W[(size_t)(k0 + kk) * N + n0 + nn];
            Bs[(size_t)(nn + 0) * 32 + kk] = (_Float16)v.x;
            Bs[(size_t)(nn + 1) * 32 + kk] = (_Float16)v.y;
            Bs[(size_t)(nn + 2) * 32 + kk] = (_Float16)v.z;
            Bs[(size_t)(nn + 3) * 32 + kk] = (_Float16)v.w;
        }
        __syncthreads();
        mfma_step_128(As, Bs, acc, lane, wr, wc);
    }

    const float s = scalep[0];
    const int colbase = n0 + wc * 64 + (lane & 15);
    const int rowbase = m0 + wr * 64 + ((lane >> 4) << 2);
#pragma unroll
    for (int ni = 0; ni < 4; ni++) {
        const int col = colbase + ni * 16;
        const float r     = rsqrtf(var[col] + 1e-5f);
        const float alpha = r * bnw[col] * s;
        const float beta  = (bias[col] - mean[col]) * alpha + bnb[col] * s;
#pragma unroll
        for (int mi = 0; mi < 4; mi++)
#pragma unroll
            for (int i = 0; i < 4; i++)
                C[(size_t)(rowbase + mi * 16 + i) * N + col] = acc[mi][ni][i] * alpha + beta;
    }
}

// ---------------------------------------------------------------- softmax

__global__ __launch_bounds__(256) void softmax_rows(float* __restrict__ out, int N) {
    __shared__ float red[8];
    float4* p = (float4*)(out + (size_t)blockIdx.x * N);
    const int t = threadIdx.x;
    const int lane = t & 63, wid = t >> 6;

    float4 v[4];
    float mx = -3.4e38f;
#pragma unroll
    for (int i = 0; i < 4; i++) {
        v[i] = p[t + 256 * i];
        mx = fmaxf(mx, fmaxf(fmaxf(v[i].x, v[i].y), fmaxf(v[i].z, v[i].w)));
    }
#pragma unroll
    for (int off = 32; off >= 1; off >>= 1) mx = fmaxf(mx, __shfl_xor(mx, off));
    if (lane == 0) red[wid] = mx;
    __syncthreads();
    mx = fmaxf(fmaxf(red[0], red[1]), fmaxf(red[2], red[3]));

    float sum = 0.f;
#pragma unroll
    for (int i = 0; i < 4; i++) {
        v[i].x = __expf(v[i].x - mx); v[i].y = __expf(v[i].y - mx);
        v[i].z = __expf(v[i].z - mx); v[i].w = __expf(v[i].w - mx);
        sum += v[i].x + v[i].y + v[i].z + v[i].w;
    }
#pragma unroll
    for (int off = 32; off >= 1; off >>= 1) sum += __shfl_xor(sum, off);
    if (lane == 0) red[4 + wid] = sum;
    __syncthreads();
    sum = red[4] + red[5] + red[6] + red[7];

    const float inv = 1.0f / sum;
#pragma unroll
    for (int i = 0; i < 4; i++) {
        v[i].x *= inv; v[i].y *= inv; v[i].z *= inv; v[i].w *= inv;
        p[t + 256 * i] = v[i];
    }
}

// ---------------------------------------------------------------- launch

extern "C" void kernel_launch(void* const* d_in, const int* in_sizes, int n_in,
                              void* d_out, int out_size, void* d_ws, size_t ws_size,
                              hipStream_t stream) {
    const float* x     = (const float*)d_in[0];
    const float* w     = (const float*)d_in[1];
    const float* bias  = (const float*)d_in[2];
    const float* mean  = (const float*)d_in[3];
    const float* var   = (const float*)d_in[4];
    const float* bnw   = (const float*)d_in[5];
    const float* bnb   = (const float*)d_in[6];
    const float* scale = (const float*)d_in[7];
    float* out = (float*)d_out;

    const int N = in_sizes[2];
    const int K = in_sizes[1] / N;
    const int M = in_sizes[0] / K;

    const size_t xh_bytes = (size_t)M * K * sizeof(_Float16);
    const size_t wh_bytes = (size_t)N * K * sizeof(_Float16);
    const int NT = K >> 5;

    if (ws_size >= xh_bytes + wh_bytes && (M & 255) == 0 && (N & 255) == 0 &&
        NT >= 2 && (K & 31) == 0) {
        _Float16* x16 = (_Float16*)d_ws;
        _Float16* wt16 = (_Float16*)((char*)d_ws + xh_bytes);
        cvt_x_kernel<<<2048, 256, 0, stream>>>((const float4*)x, (f16x4*)x16,
                                               (long)M * K / 4);
        transpose_w_kernel<<<dim3(N / 32, K / 32), dim3(32, 8), 0, stream>>>(w, wt16, K, N);
        const int nblocks = (M >> 8) * (N >> 8);
        gemm_f16_bn_db<<<nblocks, 512, 0, stream>>>(x16, wt16, out, bias, mean, var,
                                                    bnw, bnb, scale, M, N, K);
    } else {
        const int nblocks = (M / 128) * (N / 128);
        gemm_f32src_bn<<<nblocks, 256, 0, stream>>>(x, w, out, bias, mean, var,
                                                    bnw, bnb, scale, M, N, K);
    }
    softmax_rows<<<M, 256, 0, stream>>>(out, N);
}

// Round 12
// 778.024 us; speedup vs baseline: 1.0320x; 1.0320x over previous
//
#include <hip/hip_runtime.h>

typedef _Float16 f16x8  __attribute__((ext_vector_type(8)));
typedef _Float16 f16x4  __attribute__((ext_vector_type(4)));
typedef float    f32x4  __attribute__((ext_vector_type(4)));
typedef float    f32x16 __attribute__((ext_vector_type(16)));

// ---------------------------------------------------------------- helpers

__device__ __forceinline__ void async16(void* lds, const void* g) {
    __builtin_amdgcn_global_load_lds(
        (const __attribute__((address_space(1))) unsigned int*)g,
        (__attribute__((address_space(3))) unsigned int*)lds, 16, 0, 0);
}

#define MEMF() asm volatile("" ::: "memory")
__device__ __forceinline__ void BAR() { MEMF(); __builtin_amdgcn_s_barrier(); MEMF(); }
#define VMWAIT(N) asm volatile("s_waitcnt vmcnt(" #N ")" ::: "memory")

// swizzled LDS fragment read: tile row-major [256 rows][64B], 16B slot sigma
// XORed by (row>>1)&3 -> for the 32x32 pattern (row=lane&31, sigma=lh+2ks):
// 8 bank-quads x 8 lanes = 2 lanes/bank = free (m136). Same involution as the
// r4/r8 staging pre-XOR (measured 0 conflicts there).
__device__ __forceinline__ f16x8 frag32(const _Float16* buf, int row, int sigma) {
    const char* p = (const char*)buf + row * 64 + (((sigma) ^ ((row >> 1) & 3)) << 4);
    return *(const f16x8*)p;
}

// ------------------------------------------------- r8 skeleton + 32x32x16 MFMA
// A [M][K] fp16, BT [N][K] fp16, z = (A*BT^T)*alpha+beta -> fp32 C or fp16 Z
// 8 waves (2Mx4N, wave owns 128x64), BK=32, ring-4 LDS (128KiB),
// 2 barriers + vmcnt(8) per tile, all 12 frag reads front-loaded.
// Shape change vs r8: v_mfma_f32_32x32x16_f16 (2382 vs 2075 TF ubench; 16 vs
// 32 MFMA instr/wave-tile). Operand/C-D mapping hardware-verified in r6.
//
// Ledger (r8, unchanged): tile t in slot t&3; stage t+3 during t. WAR: slot
// rewritten by t+4 after BAR(end t) which follows all tile-t reads. RAW:
// VMWAIT(8) before BAR(end t) leaves {t+2,t+3} outstanding => t+1 resident.

__global__ __launch_bounds__(512, 2) void gemm_f16_bn_32(
        const _Float16* __restrict__ A, const _Float16* __restrict__ BT,
        float* __restrict__ C, _Float16* __restrict__ Z,
        const float* __restrict__ bias, const float* __restrict__ mean,
        const float* __restrict__ var,  const float* __restrict__ bnw,
        const float* __restrict__ bnb,  const float* __restrict__ scalep,
        int M, int N, int K) {
    __shared__ __align__(16) _Float16 ldsA[4][8192];   // 4 x 256x32 fp16 = 64KB
    __shared__ __align__(16) _Float16 ldsB[4][8192];   // 64KB

    // bijective XCD swizzle (grid = 1024, divisible by 8)
    const int nwg = gridDim.x;
    const int cpx = nwg >> 3;
    int bid = blockIdx.x;
    int swz = ((nwg & 7) == 0) ? (bid & 7) * cpx + (bid >> 3) : bid;
    const int ntn = N >> 8;
    const int m0 = (swz / ntn) << 8, n0 = (swz % ntn) << 8;

    const int t = threadIdx.x;
    const int lane = t & 63, wid = t >> 6;
    const int wr = wid >> 2, wc = wid & 3;          // 2M x 4N waves
    const int l31 = lane & 31, lh = lane >> 5;
    const int arow = wr * 128 + l31, brow = wc * 64 + l31;

    // staging: identical to r8 (measured 0 conflicts). 1024 16B-chunks per
    // operand tile; thread owns chunks t, t+512; LDS dest linear, global
    // source 16B-slot pre-XORed by (row>>1)&3 (both-sides involution).
    const int c0 = t, c1 = t + 512;
    const int r0 = c0 >> 2, r1 = c1 >> 2;
    const int sc0 = (((c0 & 3) << 4) ^ (((r0 >> 1) & 3) << 4)) >> 1;
    const int sc1 = (((c1 & 3) << 4) ^ (((r1 >> 1) & 3) << 4)) >> 1;
    const _Float16* gA0 = A  + (size_t)(m0 + r0) * K + sc0;
    const _Float16* gA1 = A  + (size_t)(m0 + r1) * K + sc1;
    const _Float16* gB0 = BT + (size_t)(n0 + r0) * K + sc0;
    const _Float16* gB1 = BT + (size_t)(n0 + r1) * K + sc1;
    char* const adst0 = (char*)&ldsA[0][0] + (size_t)c0 * 16;
    char* const adst1 = (char*)&ldsA[0][0] + (size_t)c1 * 16;
    char* const bdst0 = (char*)&ldsB[0][0] + (size_t)c0 * 16;
    char* const bdst1 = (char*)&ldsB[0][0] + (size_t)c1 * 16;

    f32x16 acc[4][2] = {};   // 4 m-blocks x 2 n-blocks of 32x32

    const int NT = K >> 5;   // 128

    // prologue: stage tiles 0,1,2 (tile order = FIFO vmcnt order)
#pragma unroll
    for (int ts = 0; ts < 3; ++ts) {
        async16(adst0 + ts * 16384, gA0 + ts * 32);
        async16(adst1 + ts * 16384, gA1 + ts * 32);
        async16(bdst0 + ts * 16384, gB0 + ts * 32);
        async16(bdst1 + ts * 16384, gB1 + ts * 32);
    }
    VMWAIT(8);        // own tile-0 loads done (tiles 1,2 = 8 still in flight)
    BAR();            // => everyone's tile-0 loads done

#define TILE_STEP(SLOT, STAGE, KSRC, WAITSTMT)                                   \
  do {                                                                           \
    const _Float16* Ab = ldsA[SLOT];                                             \
    const _Float16* Bb = ldsB[SLOT];                                             \
    f16x8 af[2][4], bf[2][2];                                                    \
    /* all 12 frag reads front-loaded (r8 discipline) */                         \
    _Pragma("unroll")                                                            \
    for (int ks = 0; ks < 2; ks++) {                                             \
      _Pragma("unroll")                                                          \
      for (int mi = 0; mi < 4; mi++)                                             \
        af[ks][mi] = frag32(Ab, arow + mi * 32, lh + 2 * ks);                    \
      _Pragma("unroll")                                                          \
      for (int ni = 0; ni < 2; ni++)                                             \
        bf[ks][ni] = frag32(Bb, brow + ni * 32, lh + 2 * ks);                    \
    }                                                                            \
    if (STAGE) {                                                                 \
      const int qs = (KSRC) & 3;                                                 \
      async16(adst0 + qs * 16384, gA0 + (size_t)(KSRC) * 32);                    \
      async16(adst1 + qs * 16384, gA1 + (size_t)(KSRC) * 32);                    \
    }                                                                            \
    BAR();                                                                       \
    __builtin_amdgcn_s_setprio(1);                                               \
    _Pragma("unroll")                                                            \
    for (int ni = 0; ni < 2; ni++) {                                             \
      _Pragma("unroll")                                                          \
      for (int mi = 0; mi < 4; mi++)                                             \
        acc[mi][ni] = __builtin_amdgcn_mfma_f32_32x32x16_f16(                    \
            af[0][mi], bf[0][ni], acc[mi][ni], 0, 0, 0);                         \
    }                                                                            \
    if (STAGE) {                                                                 \
      const int qs = (KSRC) & 3;                                                 \
      async16(bdst0 + qs * 16384, gB0 + (size_t)(KSRC) * 32);                    \
      async16(bdst1 + qs * 16384, gB1 + (size_t)(KSRC) * 32);                    \
    }                                                                            \
    _Pragma("unroll")                                                            \
    for (int ni = 0; ni < 2; ni++) {                                             \
      _Pragma("unroll")                                                          \
      for (int mi = 0; mi < 4; mi++)                                             \
        acc[mi][ni] = __builtin_amdgcn_mfma_f32_32x32x16_f16(                    \
            af[1][mi], bf[1][ni], acc[mi][ni], 0, 0, 0);                         \
    }                                                                            \
    __builtin_amdgcn_s_setprio(0);                                               \
    WAITSTMT;                                                                    \
    BAR();                                                                       \
  } while (0)

    int ti = 0;
    for (; ti < NT - 3; ++ti)
        TILE_STEP(ti & 3, 1, ti + 3, VMWAIT(8));
    TILE_STEP(ti & 3, 0, 0, VMWAIT(4)); ++ti;
    TILE_STEP(ti & 3, 0, 0, VMWAIT(0)); ++ti;
    TILE_STEP(ti & 3, 0, 0, (void)0);
#undef TILE_STEP

    // fused BN-affine epilogue. C/D 32x32 layout (m74/m101, r6-verified):
    // col = lane&31, row = (r&3) + 8*(r>>2) + 4*(lane>>5).
    const float s = scalep[0];
#pragma unroll
    for (int ni = 0; ni < 2; ni++) {
        const int col = n0 + wc * 64 + ni * 32 + l31;
        const float rv    = rsqrtf(var[col] + 1e-5f);
        const float alpha = rv * bnw[col] * s;
        const float beta  = (bias[col] - mean[col]) * alpha + bnb[col] * s;
#pragma unroll
        for (int mi = 0; mi < 4; mi++) {
            const int rowb = m0 + wr * 128 + mi * 32 + 4 * lh;
#pragma unroll
            for (int r = 0; r < 16; r++) {
                const int row = rowb + (r & 3) + 8 * (r >> 2);
                const float v = acc[mi][ni][r] * alpha + beta;
                if (Z) Z[(size_t)row * N + col] = (_Float16)v;
                else   __builtin_nontemporal_store(v, &C[(size_t)row * N + col]);
            }
        }
    }
}

// ---------------------------------------------------------------- converts

__global__ __launch_bounds__(256) void cvt_x_kernel(const float4* __restrict__ in,
                                                    f16x4* __restrict__ outp, long n4) {
    long i = (long)blockIdx.x * blockDim.x + threadIdx.x;
    const long stride = (long)gridDim.x * blockDim.x;
    for (; i < n4; i += stride) {
        float4 v = in[i];
        f16x4 h = { (_Float16)v.x, (_Float16)v.y, (_Float16)v.z, (_Float16)v.w };
        outp[i] = h;
    }
}

// w [K][N] fp32 -> wt [N][K] fp16
__global__ __launch_bounds__(256) void transpose_w_kernel(const float* __restrict__ w,
                                                          _Float16* __restrict__ wt,
                                                          int K, int N) {
    __shared__ _Float16 tile[32][33];
    const int n0 = blockIdx.x * 32;
    const int k0 = blockIdx.y * 32;
    for (int i = threadIdx.y; i < 32; i += 8)
        tile[i][threadIdx.x] = (_Float16)w[(size_t)(k0 + i) * N + n0 + threadIdx.x];
    __syncthreads();
    for (int i = threadIdx.y; i < 32; i += 8)
        wt[(size_t)(n0 + i) * K + k0 + threadIdx.x] = tile[threadIdx.x][i];
}

// ------------------------------------------------- fallback GEMM (no ws)

__device__ __forceinline__ void mfma_step_128(const _Float16* As, const _Float16* Bs,
                                              f32x4 (&acc)[4][4], int lane, int wr, int wc) {
    const int kk = (lane >> 4) * 8;
    const int rr = lane & 15;
    f16x8 af[4], bf[4];
#pragma unroll
    for (int mi = 0; mi < 4; mi++)
        af[mi] = *(const f16x8*)(As + (size_t)(wr * 64 + mi * 16 + rr) * 32 + kk);
#pragma unroll
    for (int ni = 0; ni < 4; ni++)
        bf[ni] = *(const f16x8*)(Bs + (size_t)(wc * 64 + ni * 16 + rr) * 32 + kk);
#pragma unroll
    for (int mi = 0; mi < 4; mi++)
#pragma unroll
        for (int ni = 0; ni < 4; ni++)
            acc[mi][ni] = __builtin_amdgcn_mfma_f32_16x16x32_f16(af[mi], bf[ni], acc[mi][ni], 0, 0, 0);
}

__global__ __launch_bounds__(256) void gemm_f32src_bn(const float* __restrict__ X,
                                                      const float* __restrict__ W,
                                                      float* __restrict__ C,
                                                      const float* __restrict__ bias,
                                                      const float* __restrict__ mean,
                                                      const float* __restrict__ var,
                                                      const float* __restrict__ bnw,
                                                      const float* __restrict__ bnb,
                                                      const float* __restrict__ scalep,
                                                      int M, int N, int K) {
    __shared__ _Float16 As[128 * 32];
    __shared__ _Float16 Bs[128 * 32];

    const int nwg = gridDim.x;
    const int cpx = nwg >> 3;
    int bid = blockIdx.x;
    int swz = ((nwg & 7) == 0) ? (bid & 7) * cpx + (bid >> 3) : bid;
    const int ntn = N / 128;
    const int m0 = (swz / ntn) * 128, n0 = (swz % ntn) * 128;

    const int t = threadIdx.x;
    const int lane = t & 63, w = t >> 6;
    const int wr = w >> 1, wc = w & 1;

    f32x4 acc[4][4] = {};

    for (int k0 = 0; k0 < K; k0 += 32) {
        __syncthreads();
#pragma unroll
        for (int p = 0; p < 4; p++) {
            const int r = p * 32 + (t >> 3);
            const int c = (t & 7) * 4;
            float4 v = *(const float4*)&X[(size_t)(m0 + r) * K + k0 + c];
            f16x4 h = { (_Float16)v.x, (_Float16)v.y, (_Float16)v.z, (_Float16)v.w };
            *(f16x4*)&As[(size_t)r * 32 + c] = h;
        }
#pragma unroll
        for (int p = 0; p < 4; p++) {
            const int kk = p * 8 + (t >> 5);
            const int nn = (t & 31) * 4;
            float4 v = *(const float4*)&W[(size_t)(k0 + kk) * N + n0 + nn];
            Bs[(size_t)(nn + 0) * 32 + kk] = (_Float16)v.x;
            Bs[(size_t)(nn + 1) * 32 + kk] = (_Float16)v.y;
            Bs[(size_t)(nn + 2) * 32 + kk] = (_Float16)v.z;
            Bs[(size_t)(nn + 3) * 32 + kk] = (_Float16)v.w;
        }
        __syncthreads();
        mfma_step_128(As, Bs, acc, lane, wr, wc);
    }

    const float s = scalep[0];
    const int colbase = n0 + wc * 64 + (lane & 15);
    const int rowbase = m0 + wr * 64 + ((lane >> 4) << 2);
#pragma unroll
    for (int ni = 0; ni < 4; ni++) {
        const int col = colbase + ni * 16;
        const float r     = rsqrtf(var[col] + 1e-5f);
        const float alpha = r * bnw[col] * s;
        const float beta  = (bias[col] - mean[col]) * alpha + bnb[col] * s;
#pragma unroll
        for (int mi = 0; mi < 4; mi++)
#pragma unroll
            for (int i = 0; i < 4; i++)
                C[(size_t)(rowbase + mi * 16 + i) * N + col] = acc[mi][ni][i] * alpha + beta;
    }
}

// ---------------------------------------------------------------- softmax

__global__ __launch_bounds__(256) void softmax_rows(float* __restrict__ out, int N) {
    __shared__ float red[8];
    float4* p = (float4*)(out + (size_t)blockIdx.x * N);
    const int t = threadIdx.x;
    const int lane = t & 63, wid = t >> 6;

    float4 v[4];
    float mx = -3.4e38f;
#pragma unroll
    for (int i = 0; i < 4; i++) {
        v[i] = p[t + 256 * i];
        mx = fmaxf(mx, fmaxf(fmaxf(v[i].x, v[i].y), fmaxf(v[i].z, v[i].w)));
    }
#pragma unroll
    for (int off = 32; off >= 1; off >>= 1) mx = fmaxf(mx, __shfl_xor(mx, off));
    if (lane == 0) red[wid] = mx;
    __syncthreads();
    mx = fmaxf(fmaxf(red[0], red[1]), fmaxf(red[2], red[3]));

    float sum = 0.f;
#pragma unroll
    for (int i = 0; i < 4; i++) {
        v[i].x = __expf(v[i].x - mx); v[i].y = __expf(v[i].y - mx);
        v[i].z = __expf(v[i].z - mx); v[i].w = __expf(v[i].w - mx);
        sum += v[i].x + v[i].y + v[i].z + v[i].w;
    }
#pragma unroll
    for (int off = 32; off >= 1; off >>= 1) sum += __shfl_xor(sum, off);
    if (lane == 0) red[4 + wid] = sum;
    __syncthreads();
    sum = red[4] + red[5] + red[6] + red[7];

    const float inv = 1.0f / sum;
#pragma unroll
    for (int i = 0; i < 4; i++) {
        v[i].x *= inv; v[i].y *= inv; v[i].z *= inv; v[i].w *= inv;
        p[t + 256 * i] = v[i];
    }
}

// fp16-z variant: reads z fp16 (half the read bytes), writes fp32 probs
__global__ __launch_bounds__(256) void softmax_rows_h(const _Float16* __restrict__ z,
                                                      float* __restrict__ out, int N) {
    __shared__ float red[8];
    const _Float16* zr = z + (size_t)blockIdx.x * N;
    float4* o4 = (float4*)(out + (size_t)blockIdx.x * N);
    const int t = threadIdx.x;
    const int lane = t & 63, wid = t >> 6;

    f16x8 h0 = *(const f16x8*)(zr + t * 8);
    f16x8 h1 = *(const f16x8*)(zr + 2048 + t * 8);
    float v[16];
#pragma unroll
    for (int i = 0; i < 8; i++) { v[i] = (float)h0[i]; v[8 + i] = (float)h1[i]; }

    float mx = -3.4e38f;
#pragma unroll
    for (int i = 0; i < 16; i++) mx = fmaxf(mx, v[i]);
#pragma unroll
    for (int off = 32; off >= 1; off >>= 1) mx = fmaxf(mx, __shfl_xor(mx, off));
    if (lane == 0) red[wid] = mx;
    __syncthreads();
    mx = fmaxf(fmaxf(red[0], red[1]), fmaxf(red[2], red[3]));

    float sum = 0.f;
#pragma unroll
    for (int i = 0; i < 16; i++) { v[i] = __expf(v[i] - mx); sum += v[i]; }
#pragma unroll
    for (int off = 32; off >= 1; off >>= 1) sum += __shfl_xor(sum, off);
    if (lane == 0) red[4 + wid] = sum;
    __syncthreads();
    sum = red[4] + red[5] + red[6] + red[7];

    const float inv = 1.0f / sum;
    float4 o;
#pragma unroll
    for (int c = 0; c < 4; c++) {
        o.x = v[c * 4 + 0] * inv; o.y = v[c * 4 + 1] * inv;
        o.z = v[c * 4 + 2] * inv; o.w = v[c * 4 + 3] * inv;
        o4[(c >> 1) * 512 + t * 2 + (c & 1)] = o;
    }
}

// ---------------------------------------------------------------- launch

extern "C" void kernel_launch(void* const* d_in, const int* in_sizes, int n_in,
                              void* d_out, int out_size, void* d_ws, size_t ws_size,
                              hipStream_t stream) {
    const float* x     = (const float*)d_in[0];
    const float* w     = (const float*)d_in[1];
    const float* bias  = (const float*)d_in[2];
    const float* mean  = (const float*)d_in[3];
    const float* var   = (const float*)d_in[4];
    const float* bnw   = (const float*)d_in[5];
    const float* bnb   = (const float*)d_in[6];
    const float* scale = (const float*)d_in[7];
    float* out = (float*)d_out;

    const int N = in_sizes[2];
    const int K = in_sizes[1] / N;
    const int M = in_sizes[0] / K;

    const size_t xh_bytes = (size_t)M * K * sizeof(_Float16);
    const size_t wh_bytes = (size_t)N * K * sizeof(_Float16);
    const size_t zh_bytes = (size_t)M * N * sizeof(_Float16);
    const int NT = K >> 5;

    if (ws_size >= xh_bytes + wh_bytes && (M & 255) == 0 && (N & 255) == 0 &&
        NT >= 8 && (K & 31) == 0 && (N & 4095) == 0) {
        _Float16* x16 = (_Float16*)d_ws;
        _Float16* wt16 = (_Float16*)((char*)d_ws + xh_bytes);
        const bool zf16 = ws_size >= xh_bytes + wh_bytes + zh_bytes;
        _Float16* z16 = zf16 ? (_Float16*)((char*)d_ws + xh_bytes + wh_bytes) : nullptr;

        cvt_x_kernel<<<2048, 256, 0, stream>>>((const float4*)x, (f16x4*)x16,
                                               (long)M * K / 4);
        transpose_w_kernel<<<dim3(N / 32, K / 32), dim3(32, 8), 0, stream>>>(w, wt16, K, N);
        const int nblocks = (M >> 8) * (N >> 8);
        gemm_f16_bn_32<<<nblocks, 512, 0, stream>>>(x16, wt16, out, z16, bias, mean,
                                                    var, bnw, bnb, scale, M, N, K);
        if (zf16) softmax_rows_h<<<M, 256, 0, stream>>>(z16, out, N);
        else      softmax_rows<<<M, 256, 0, stream>>>(out, N);
    } else {
        const int nblocks = (M / 128) * (N / 128);
        gemm_f32src_bn<<<nblocks, 256, 0, stream>>>(x, w, out, bias, mean, var,
                                                    bnw, bnb, scale, M, N, K);
        softmax_rows<<<M, 256, 0, stream>>>(out, N);
    }
}

// Round 13
// 766.939 us; speedup vs baseline: 1.0469x; 1.0145x over previous
//
#include <hip/hip_runtime.h>

typedef _Float16 f16x8 __attribute__((ext_vector_type(8)));
typedef _Float16 f16x4 __attribute__((ext_vector_type(4)));
typedef float    f32x4 __attribute__((ext_vector_type(4)));

// ---------------------------------------------------------------- helpers

__device__ __forceinline__ void async16(void* lds, const void* g) {
    __builtin_amdgcn_global_load_lds(
        (const __attribute__((address_space(1))) unsigned int*)g,
        (__attribute__((address_space(3))) unsigned int*)lds, 16, 0, 0);
}

#define MEMF() asm volatile("" ::: "memory")
__device__ __forceinline__ void BAR() { MEMF(); __builtin_amdgcn_s_barrier(); MEMF(); }
#define VMWAIT(N) asm volatile("s_waitcnt vmcnt(" #N ")" ::: "memory")

// swizzled LDS fragment read: tile row-major [256 rows][64B], byte col XORed by
// ((row>>1)&3)<<4 -> conflict-free for the 16x16 pattern (4 distinct kq per
// row); measured 0 in SQ_LDS_BANK_CONFLICT (r4/r8). 32x32 pattern conflicts
// structurally (r6/r12: 5.03e7) -- do not use that shape with this layout.
__device__ __forceinline__ f16x8 frag_ld(const _Float16* buf, int row, int kq) {
    const char* p = (const char*)buf + row * 64 + ((kq << 4) ^ (((row >> 1) & 3) << 4));
    return *(const f16x8*)p;
}

// ------------------------------------------------- r8 2-barrier 256x256 GEMM
// A [M][K] fp16, BT [N][K] fp16, z = (A*BT^T)*alpha+beta -> fp16 Z (ws) or fp32 C
// 8 waves (2Mx4N), BK=32, ring-4 LDS (128KiB), 2 barriers + vmcnt(8)/tile,
// all 12 frag reads front-loaded, mfma 16x16x32. Best-measured K-loop (590us,
// 916 TF, MfmaUtil 40, 0 conflicts) across 9 structural variants (r4-r12).
//
// Ledger: tile t in slot t&3; stage t+3 during t. WAR: wave w's tile-(t-1)
// reads lgkm-drain before its MFMA cluster, which precedes BAR_b(t-1), which
// precedes every wave's stage(t+3) into slot (t-1) => safe. RAW: VMWAIT(8)
// before BAR_b(t-1) leaves only {t+1,t+2} outstanding => tile t resident for
// all waves when its reads begin. Tail: peel 3 tiles, waits 4/0/none.

__global__ __launch_bounds__(512, 2) void gemm_f16_bn_8p(
        const _Float16* __restrict__ A, const _Float16* __restrict__ BT,
        float* __restrict__ C, _Float16* __restrict__ Z,
        const float* __restrict__ bias, const float* __restrict__ mean,
        const float* __restrict__ var,  const float* __restrict__ bnw,
        const float* __restrict__ bnb,  const float* __restrict__ scalep,
        int M, int N, int K) {
    __shared__ __align__(16) _Float16 ldsA[4][8192];   // 4 x 256x32 fp16 = 64KB
    __shared__ __align__(16) _Float16 ldsB[4][8192];   // 64KB

    // bijective XCD swizzle (grid = 1024, divisible by 8)
    const int nwg = gridDim.x;
    const int cpx = nwg >> 3;
    int bid = blockIdx.x;
    int swz = ((nwg & 7) == 0) ? (bid & 7) * cpx + (bid >> 3) : bid;
    const int ntn = N >> 8;
    const int m0 = (swz / ntn) << 8, n0 = (swz % ntn) << 8;

    const int t = threadIdx.x;
    const int lane = t & 63, wid = t >> 6;
    const int wr = wid >> 2, wc = wid & 3;          // 2M x 4N waves
    const int rr = lane & 15, kq = lane >> 4;
    const int arow = wr * 128, brow = wc * 64;

    // staging: 1024 16B-chunks per operand tile; thread handles chunks t, t+512.
    // chunk c -> LDS bytes [c*16, c*16+16) (linear); source column pre-XORed so
    // the swizzled read returns linear data (both-sides-or-neither).
    const int c0 = t, c1 = t + 512;
    const int r0 = c0 >> 2, r1 = c1 >> 2;
    const int sc0 = (((c0 & 3) << 4) ^ (((r0 >> 1) & 3) << 4)) >> 1;
    const int sc1 = (((c1 & 3) << 4) ^ (((r1 >> 1) & 3) << 4)) >> 1;
    const _Float16* gA0 = A  + (size_t)(m0 + r0) * K + sc0;
    const _Float16* gA1 = A  + (size_t)(m0 + r1) * K + sc1;
    const _Float16* gB0 = BT + (size_t)(n0 + r0) * K + sc0;
    const _Float16* gB1 = BT + (size_t)(n0 + r1) * K + sc1;
    char* const adst0 = (char*)&ldsA[0][0] + (size_t)c0 * 16;
    char* const adst1 = (char*)&ldsA[0][0] + (size_t)c1 * 16;
    char* const bdst0 = (char*)&ldsB[0][0] + (size_t)c0 * 16;
    char* const bdst1 = (char*)&ldsB[0][0] + (size_t)c1 * 16;

    f32x4 acc[8][4] = {};

    const int NT = K >> 5;   // 128

    // prologue: stage tiles 0,1,2 (tile order = FIFO vmcnt order)
#pragma unroll
    for (int ts = 0; ts < 3; ++ts) {
        async16(adst0 + ts * 16384, gA0 + ts * 32);
        async16(adst1 + ts * 16384, gA1 + ts * 32);
        async16(bdst0 + ts * 16384, gB0 + ts * 32);
        async16(bdst1 + ts * 16384, gB1 + ts * 32);
    }
    VMWAIT(8);        // own tile-0 loads done (tiles 1,2 = 8 still in flight)
    BAR();            // => everyone's tile-0 loads done

#define TILE_STEP(SLOT, STAGE, KSRC, WAITSTMT)                                   \
  do {                                                                           \
    const _Float16* Ab = ldsA[SLOT];                                             \
    const _Float16* Bb = ldsB[SLOT];                                             \
    f16x8 af[8], bf[4];                                                          \
    /* all 12 frag reads front-loaded: waves stagger on their own lgkm waits */  \
    _Pragma("unroll")                                                            \
    for (int mi = 0; mi < 8; mi++) af[mi] = frag_ld(Ab, arow + mi * 16 + rr, kq);\
    _Pragma("unroll")                                                            \
    for (int ni = 0; ni < 4; ni++) bf[ni] = frag_ld(Bb, brow + ni * 16 + rr, kq);\
    if (STAGE) {                                                                 \
      const int qs = (KSRC) & 3;                                                 \
      async16(adst0 + qs * 16384, gA0 + (size_t)(KSRC) * 32);                    \
      async16(adst1 + qs * 16384, gA1 + (size_t)(KSRC) * 32);                    \
    }                                                                            \
    BAR();                                                                       \
    __builtin_amdgcn_s_setprio(1);                                               \
    _Pragma("unroll")                                                            \
    for (int ni = 0; ni < 2; ni++) {                                             \
      _Pragma("unroll")                                                          \
      for (int mi = 0; mi < 8; mi++)                                             \
        acc[mi][ni] = __builtin_amdgcn_mfma_f32_16x16x32_f16(                    \
            af[mi], bf[ni], acc[mi][ni], 0, 0, 0);                               \
    }                                                                            \
    if (STAGE) {                                                                 \
      const int qs = (KSRC) & 3;                                                 \
      async16(bdst0 + qs * 16384, gB0 + (size_t)(KSRC) * 32);                    \
      async16(bdst1 + qs * 16384, gB1 + (size_t)(KSRC) * 32);                    \
    }                                                                            \
    _Pragma("unroll")                                                            \
    for (int ni = 2; ni < 4; ni++) {                                             \
      _Pragma("unroll")                                                          \
      for (int mi = 0; mi < 8; mi++)                                             \
        acc[mi][ni] = __builtin_amdgcn_mfma_f32_16x16x32_f16(                    \
            af[mi], bf[ni], acc[mi][ni], 0, 0, 0);                               \
    }                                                                            \
    __builtin_amdgcn_s_setprio(0);                                               \
    WAITSTMT;                                                                    \
    BAR();                                                                       \
  } while (0)

    int ti = 0;
    for (; ti < NT - 3; ++ti)
        TILE_STEP(ti & 3, 1, ti + 3, VMWAIT(8));
    TILE_STEP(ti & 3, 0, 0, VMWAIT(4)); ++ti;
    TILE_STEP(ti & 3, 0, 0, VMWAIT(0)); ++ti;
    TILE_STEP(ti & 3, 0, 0, (void)0);
#undef TILE_STEP

    // fused BN-affine epilogue: fp16 z to ws (softmax re-reads) or fp32 C
    const float s = scalep[0];
    const int colb = n0 + wc * 64 + rr;
    const int rowb = m0 + wr * 128 + (kq << 2);
#pragma unroll
    for (int ni = 0; ni < 4; ni++) {
        const int col = colb + ni * 16;
        const float rv    = rsqrtf(var[col] + 1e-5f);
        const float alpha = rv * bnw[col] * s;
        const float beta  = (bias[col] - mean[col]) * alpha + bnb[col] * s;
#pragma unroll
        for (int mi = 0; mi < 8; mi++)
#pragma unroll
            for (int i = 0; i < 4; i++) {
                const float v = acc[mi][ni][i] * alpha + beta;
                const size_t off = (size_t)(rowb + mi * 16 + i) * N + col;
                if (Z) Z[off] = (_Float16)v;
                else   __builtin_nontemporal_store(v, &C[off]);
            }
    }
}

// ---------------------------------------------------------------- converts

__global__ __launch_bounds__(256) void cvt_x_kernel(const float4* __restrict__ in,
                                                    f16x4* __restrict__ outp, long n4) {
    long i = (long)blockIdx.x * blockDim.x + threadIdx.x;
    const long stride = (long)gridDim.x * blockDim.x;
    for (; i < n4; i += stride) {
        float4 v = in[i];
        f16x4 h = { (_Float16)v.x, (_Float16)v.y, (_Float16)v.z, (_Float16)v.w };
        outp[i] = h;
    }
}

// w [K][N] fp32 -> wt [N][K] fp16
__global__ __launch_bounds__(256) void transpose_w_kernel(const float* __restrict__ w,
                                                          _Float16* __restrict__ wt,
                                                          int K, int N) {
    __shared__ _Float16 tile[32][33];
    const int n0 = blockIdx.x * 32;
    const int k0 = blockIdx.y * 32;
    for (int i = threadIdx.y; i < 32; i += 8)
        tile[i][threadIdx.x] = (_Float16)w[(size_t)(k0 + i) * N + n0 + threadIdx.x];
    __syncthreads();
    for (int i = threadIdx.y; i < 32; i += 8)
        wt[(size_t)(n0 + i) * K + k0 + threadIdx.x] = tile[threadIdx.x][i];
}

// ------------------------------------------------- fallback GEMM (no ws)

__device__ __forceinline__ void mfma_step_128(const _Float16* As, const _Float16* Bs,
                                              f32x4 (&acc)[4][4], int lane, int wr, int wc) {
    const int kk = (lane >> 4) * 8;
    const int rr = lane & 15;
    f16x8 af[4], bf[4];
#pragma unroll
    for (int mi = 0; mi < 4; mi++)
        af[mi] = *(const f16x8*)(As + (size_t)(wr * 64 + mi * 16 + rr) * 32 + kk);
#pragma unroll
    for (int ni = 0; ni < 4; ni++)
        bf[ni] = *(const f16x8*)(Bs + (size_t)(wc * 64 + ni * 16 + rr) * 32 + kk);
#pragma unroll
    for (int mi = 0; mi < 4; mi++)
#pragma unroll
        for (int ni = 0; ni < 4; ni++)
            acc[mi][ni] = __builtin_amdgcn_mfma_f32_16x16x32_f16(af[mi], bf[ni], acc[mi][ni], 0, 0, 0);
}

__global__ __launch_bounds__(256) void gemm_f32src_bn(const float* __restrict__ X,
                                                      const float* __restrict__ W,
                                                      float* __restrict__ C,
                                                      const float* __restrict__ bias,
                                                      const float* __restrict__ mean,
                                                      const float* __restrict__ var,
                                                      const float* __restrict__ bnw,
                                                      const float* __restrict__ bnb,
                                                      const float* __restrict__ scalep,
                                                      int M, int N, int K) {
    __shared__ _Float16 As[128 * 32];
    __shared__ _Float16 Bs[128 * 32];

    const int nwg = gridDim.x;
    const int cpx = nwg >> 3;
    int bid = blockIdx.x;
    int swz = ((nwg & 7) == 0) ? (bid & 7) * cpx + (bid >> 3) : bid;
    const int ntn = N / 128;
    const int m0 = (swz / ntn) * 128, n0 = (swz % ntn) * 128;

    const int t = threadIdx.x;
    const int lane = t & 63, w = t >> 6;
    const int wr = w >> 1, wc = w & 1;

    f32x4 acc[4][4] = {};

    for (int k0 = 0; k0 < K; k0 += 32) {
        __syncthreads();
#pragma unroll
        for (int p = 0; p < 4; p++) {
            const int r = p * 32 + (t >> 3);
            const int c = (t & 7) * 4;
            float4 v = *(const float4*)&X[(size_t)(m0 + r) * K + k0 + c];
            f16x4 h = { (_Float16)v.x, (_Float16)v.y, (_Float16)v.z, (_Float16)v.w };
            *(f16x4*)&As[(size_t)r * 32 + c] = h;
        }
#pragma unroll
        for (int p = 0; p < 4; p++) {
            const int kk = p * 8 + (t >> 5);
            const int nn = (t & 31) * 4;
            float4 v = *(const float4*)&W[(size_t)(k0 + kk) * N + n0 + nn];
            Bs[(size_t)(nn + 0) * 32 + kk] = (_Float16)v.x;
            Bs[(size_t)(nn + 1) * 32 + kk] = (_Float16)v.y;
            Bs[(size_t)(nn + 2) * 32 + kk] = (_Float16)v.z;
            Bs[(size_t)(nn + 3) * 32 + kk] = (_Float16)v.w;
        }
        __syncthreads();
        mfma_step_128(As, Bs, acc, lane, wr, wc);
    }

    const float s = scalep[0];
    const int colbase = n0 + wc * 64 + (lane & 15);
    const int rowbase = m0 + wr * 64 + ((lane >> 4) << 2);
#pragma unroll
    for (int ni = 0; ni < 4; ni++) {
        const int col = colbase + ni * 16;
        const float r     = rsqrtf(var[col] + 1e-5f);
        const float alpha = r * bnw[col] * s;
        const float beta  = (bias[col] - mean[col]) * alpha + bnb[col] * s;
#pragma unroll
        for (int mi = 0; mi < 4; mi++)
#pragma unroll
            for (int i = 0; i < 4; i++)
                C[(size_t)(rowbase + mi * 16 + i) * N + col] = acc[mi][ni][i] * alpha + beta;
    }
}

// ---------------------------------------------------------------- softmax

__global__ __launch_bounds__(256) void softmax_rows(float* __restrict__ out, int N) {
    __shared__ float red[8];
    float4* p = (float4*)(out + (size_t)blockIdx.x * N);
    const int t = threadIdx.x;
    const int lane = t & 63, wid = t >> 6;

    float4 v[4];
    float mx = -3.4e38f;
#pragma unroll
    for (int i = 0; i < 4; i++) {
        v[i] = p[t + 256 * i];
        mx = fmaxf(mx, fmaxf(fmaxf(v[i].x, v[i].y), fmaxf(v[i].z, v[i].w)));
    }
#pragma unroll
    for (int off = 32; off >= 1; off >>= 1) mx = fmaxf(mx, __shfl_xor(mx, off));
    if (lane == 0) red[wid] = mx;
    __syncthreads();
    mx = fmaxf(fmaxf(red[0], red[1]), fmaxf(red[2], red[3]));

    float sum = 0.f;
#pragma unroll
    for (int i = 0; i < 4; i++) {
        v[i].x = __expf(v[i].x - mx); v[i].y = __expf(v[i].y - mx);
        v[i].z = __expf(v[i].z - mx); v[i].w = __expf(v[i].w - mx);
        sum += v[i].x + v[i].y + v[i].z + v[i].w;
    }
#pragma unroll
    for (int off = 32; off >= 1; off >>= 1) sum += __shfl_xor(sum, off);
    if (lane == 0) red[4 + wid] = sum;
    __syncthreads();
    sum = red[4] + red[5] + red[6] + red[7];

    const float inv = 1.0f / sum;
#pragma unroll
    for (int i = 0; i < 4; i++) {
        v[i].x *= inv; v[i].y *= inv; v[i].z *= inv; v[i].w *= inv;
        p[t + 256 * i] = v[i];
    }
}

// fp16-z variant: reads z fp16 (half the read bytes), writes fp32 probs
__global__ __launch_bounds__(256) void softmax_rows_h(const _Float16* __restrict__ z,
                                                      float* __restrict__ out, int N) {
    __shared__ float red[8];
    const _Float16* zr = z + (size_t)blockIdx.x * N;
    float4* o4 = (float4*)(out + (size_t)blockIdx.x * N);
    const int t = threadIdx.x;
    const int lane = t & 63, wid = t >> 6;

    f16x8 h0 = *(const f16x8*)(zr + t * 8);
    f16x8 h1 = *(const f16x8*)(zr + 2048 + t * 8);
    float v[16];
#pragma unroll
    for (int i = 0; i < 8; i++) { v[i] = (float)h0[i]; v[8 + i] = (float)h1[i]; }

    float mx = -3.4e38f;
#pragma unroll
    for (int i = 0; i < 16; i++) mx = fmaxf(mx, v[i]);
#pragma unroll
    for (int off = 32; off >= 1; off >>= 1) mx = fmaxf(mx, __shfl_xor(mx, off));
    if (lane == 0) red[wid] = mx;
    __syncthreads();
    mx = fmaxf(fmaxf(red[0], red[1]), fmaxf(red[2], red[3]));

    float sum = 0.f;
#pragma unroll
    for (int i = 0; i < 16; i++) { v[i] = __expf(v[i] - mx); sum += v[i]; }
#pragma unroll
    for (int off = 32; off >= 1; off >>= 1) sum += __shfl_xor(sum, off);
    if (lane == 0) red[4 + wid] = sum;
    __syncthreads();
    sum = red[4] + red[5] + red[6] + red[7];

    const float inv = 1.0f / sum;
    float4 o;
#pragma unroll
    for (int c = 0; c < 4; c++) {
        o.x = v[c * 4 + 0] * inv; o.y = v[c * 4 + 1] * inv;
        o.z = v[c * 4 + 2] * inv; o.w = v[c * 4 + 3] * inv;
        o4[(c >> 1) * 512 + t * 2 + (c & 1)] = o;
    }
}

// ---------------------------------------------------------------- launch

extern "C" void kernel_launch(void* const* d_in, const int* in_sizes, int n_in,
                              void* d_out, int out_size, void* d_ws, size_t ws_size,
                              hipStream_t stream) {
    const float* x     = (const float*)d_in[0];
    const float* w     = (const float*)d_in[1];
    const float* bias  = (const float*)d_in[2];
    const float* mean  = (const float*)d_in[3];
    const float* var   = (const float*)d_in[4];
    const float* bnw   = (const float*)d_in[5];
    const float* bnb   = (const float*)d_in[6];
    const float* scale = (const float*)d_in[7];
    float* out = (float*)d_out;

    const int N = in_sizes[2];
    const int K = in_sizes[1] / N;
    const int M = in_sizes[0] / K;

    const size_t xh_bytes = (size_t)M * K * sizeof(_Float16);
    const size_t wh_bytes = (size_t)N * K * sizeof(_Float16);
    const size_t zh_bytes = (size_t)M * N * sizeof(_Float16);
    const int NT = K >> 5;

    if (ws_size >= xh_bytes + wh_bytes && (M & 255) == 0 && (N & 255) == 0 &&
        NT >= 8 && (NT & 3) == 0 && (K & 31) == 0) {
        _Float16* x16 = (_Float16*)d_ws;
        _Float16* wt16 = (_Float16*)((char*)d_ws + xh_bytes);
        const bool zf16 = (ws_size >= xh_bytes + wh_bytes + zh_bytes) && (N & 4095) == 0;
        _Float16* z16 = zf16 ? (_Float16*)((char*)d_ws + xh_bytes + wh_bytes) : nullptr;

        cvt_x_kernel<<<2048, 256, 0, stream>>>((const float4*)x, (f16x4*)x16,
                                               (long)M * K / 4);
        transpose_w_kernel<<<dim3(N / 32, K / 32), dim3(32, 8), 0, stream>>>(w, wt16, K, N);
        const int nblocks = (M >> 8) * (N >> 8);
        gemm_f16_bn_8p<<<nblocks, 512, 0, stream>>>(x16, wt16, out, z16, bias, mean,
                                                    var, bnw, bnb, scale, M, N, K);
        if (zf16) softmax_rows_h<<<M, 256, 0, stream>>>(z16, out, N);
        else      softmax_rows<<<M, 256, 0, stream>>>(out, N);
    } else {
        const int nblocks = (M / 128) * (N / 128);
        gemm_f32src_bn<<<nblocks, 256, 0, stream>>>(x, w, out, bias, mean, var,
                                                    bnw, bnb, scale, M, N, K);
        softmax_rows<<<M, 256, 0, stream>>>(out, N);
    }
}